// Round 1
// baseline (3451.789 us; speedup 1.0000x reference)
//
#include <hip/hip_runtime.h>
#include <cstdint>

#define BB 8
#define NN 16384
#define CC 128
#define HEADS 2
#define HD 64
#define NK 256

// workspace offsets (in floats)
#define OFF_WT   0          // conv weight transposed: [k=p*128+c][o]  8192*128
#define OFF_PWT  1048576    // proj_w transposed: [c][o]               128*128
#define OFF_KVWT 1064960    // kv_w transposed: [c][kvo]               128*256
#define OFF_K    1097728    // [B][H][NK][HD]                          262144
#define OFF_V    1359872    // [B][H][NK][HD]                          262144

__global__ __launch_bounds__(256) void prep_w(
    const float* __restrict__ sr_w, const float* __restrict__ proj_w,
    const float* __restrict__ kv_w, float* __restrict__ ws) {
  int tid = blockIdx.x * 256 + threadIdx.x;   // grid 4096*256 = 1048576 exactly
  {
    int o = tid & 127, k = tid >> 7;
    int c = k & 127, p = k >> 7;              // p = di*8+dj
    ws[OFF_WT + tid] = sr_w[o * 8192 + c * 64 + p];
  }
  if (tid < 128 * 128) {
    int o = tid & 127, c = tid >> 7;
    ws[OFF_PWT + c * 128 + o] = proj_w[o * 128 + c];
  }
  if (tid < 256 * 128) {
    int kvo = tid & 255, c = tid >> 8;
    ws[OFF_KVWT + c * 256 + kvo] = kv_w[kvo * 128 + c];
  }
}

// 256 blocks (b, 8-token tile) x 512 threads.
// conv as GEMM: M=8 tokens, N=128 out-ch, K=8192 (pixel-major), K staged in LDS.
__global__ __launch_bounds__(512) void conv_ln_kv(
    const float* __restrict__ x, const float* __restrict__ wT,
    const float* __restrict__ kvwT, const float* __restrict__ kv_b,
    const float* __restrict__ ln_g, const float* __restrict__ ln_b,
    float* __restrict__ kbuf, float* __restrict__ vbuf) {
  __shared__ float xs[8192];      // [1024 k][8 tokens] 32KB
  __shared__ float tok[8 * 128];  // 4KB
  const int t = threadIdx.x;
  const int b = blockIdx.x >> 5;
  const int tile = blockIdx.x & 31;

  const int o  = t & 127;
  const int qq = t >> 7;     // 0..3
  const int mh = qq & 1;     // token half (4 tokens)
  const int kh = qq >> 1;    // k half

  float acc0 = 0, acc1 = 0, acc2 = 0, acc3 = 0;

  for (int kc = 0; kc < 8; ++kc) {   // 8 K-chunks of 1024 (8 pixels x 128 ch)
    __syncthreads();
    #pragma unroll
    for (int it = 0; it < 2; ++it) {
      int kl = it * 512 + t;         // 0..1023
      int c  = kl & 127;
      int pl = kl >> 7;              // 0..7
      int p  = kc * 8 + pl;
      int di = p >> 3, dj = p & 7;
      float v[8];
      #pragma unroll
      for (int tm = 0; tm < 8; ++tm) {
        int nk = tile * 8 + tm;
        int ti = nk >> 4, tj = nk & 15;
        int n  = (ti * 8 + di) * 128 + (tj * 8 + dj);
        v[tm] = x[((size_t)b * NN + n) * CC + c];
      }
      float4* dst = (float4*)&xs[kl * 8];
      dst[0] = make_float4(v[0], v[1], v[2], v[3]);
      dst[1] = make_float4(v[4], v[5], v[6], v[7]);
    }
    __syncthreads();
    const float*  wrow = wT + (size_t)(kc * 1024 + kh * 512) * 128 + o;
    const float4* xsp  = (const float4*)&xs[kh * 512 * 8 + mh * 4];
    #pragma unroll 4
    for (int kl = 0; kl < 512; ++kl) {
      float  w  = wrow[(size_t)kl * 128];
      float4 xv = xsp[kl * 2];
      acc0 += xv.x * w; acc1 += xv.y * w; acc2 += xv.z * w; acc3 += xv.w * w;
    }
  }
  if (kh == 0) {
    tok[(mh * 4 + 0) * 128 + o] = acc0; tok[(mh * 4 + 1) * 128 + o] = acc1;
    tok[(mh * 4 + 2) * 128 + o] = acc2; tok[(mh * 4 + 3) * 128 + o] = acc3;
  }
  __syncthreads();
  if (kh == 1) {
    tok[(mh * 4 + 0) * 128 + o] += acc0; tok[(mh * 4 + 1) * 128 + o] += acc1;
    tok[(mh * 4 + 2) * 128 + o] += acc2; tok[(mh * 4 + 3) * 128 + o] += acc3;
  }
  __syncthreads();
  // LayerNorm over channels, one 32-lane group per token
  if (t < 256) {
    int m = t >> 5, j = t & 31;
    float s = 0, ss = 0;
    #pragma unroll
    for (int c = j; c < 128; c += 32) { float vv = tok[m * 128 + c]; s += vv; ss += vv * vv; }
    #pragma unroll
    for (int w = 16; w; w >>= 1) { s += __shfl_xor(s, w); ss += __shfl_xor(ss, w); }
    float mu  = s * 0.0078125f;
    float var = fmaxf(ss * 0.0078125f - mu * mu, 0.f);
    float rs  = rsqrtf(var + 1e-5f);
    #pragma unroll
    for (int c = j; c < 128; c += 32) {
      float vv = tok[m * 128 + c];
      tok[m * 128 + c] = (vv - mu) * rs * ln_g[c] + ln_b[c];
    }
  }
  __syncthreads();
  // KV projection: thread = (kvo 0..255, token-half)
  {
    int kvo = t & 255, mhf = t >> 8;
    float a0 = 0, a1 = 0, a2 = 0, a3 = 0;
    for (int c = 0; c < 128; ++c) {
      float w = kvwT[c * 256 + kvo];
      a0 += tok[(mhf * 4 + 0) * 128 + c] * w;
      a1 += tok[(mhf * 4 + 1) * 128 + c] * w;
      a2 += tok[(mhf * 4 + 2) * 128 + c] * w;
      a3 += tok[(mhf * 4 + 3) * 128 + c] * w;
    }
    float bias = kv_b[kvo];
    int two = kvo >> 7, h = (kvo >> 6) & 1, d = kvo & 63;
    float* ob = two ? vbuf : kbuf;
    size_t base = (((size_t)b * HEADS + h) * NK + tile * 8 + mhf * 4) * HD + d;
    ob[base]          = a0 + bias;
    ob[base + HD]     = a1 + bias;
    ob[base + 2 * HD] = a2 + bias;
    ob[base + 3 * HD] = a3 + bias;
  }
}

// 4096 blocks: (b, h, 64-query tile) x 256 threads; 4 lanes per query.
__global__ __launch_bounds__(256) void attn_fused(
    const float* __restrict__ x, const float* __restrict__ q_w,
    const float* __restrict__ q_b, const float* __restrict__ kbuf,
    const float* __restrict__ vbuf, float* __restrict__ out) {
  __shared__ float lg[64 * 256];   // per-query logits (swizzled), 64KB
  const int t  = threadIdx.x;
  const int bx = blockIdx.x;
  const int b = bx >> 9, h = (bx >> 8) & 1, qt = bx & 255;
  const int qi = t >> 2, s = t & 3;
  const int n = qt * 64 + qi;

  // Q projection for dims [h*64 + s*16 .. +15]
  const float4* xrow = (const float4*)(x + ((size_t)b * NN + n) * CC);
  float qreg[16];
  #pragma unroll
  for (int i = 0; i < 16; ++i) qreg[i] = q_b[h * 64 + s * 16 + i];
  for (int c4 = 0; c4 < 32; ++c4) {
    float4 xv = xrow[c4];
    #pragma unroll
    for (int i = 0; i < 16; ++i) {
      float4 wv = ((const float4*)(q_w + (size_t)(h * 64 + s * 16 + i) * CC))[c4];
      qreg[i] += xv.x * wv.x + xv.y * wv.y + xv.z * wv.z + xv.w * wv.w;
    }
  }
  #pragma unroll
  for (int i = 0; i < 16; ++i) qreg[i] *= 0.125f;  // fold SCALE

  // logits: each lane does 16 of 64 dims, butterfly-reduce over 4 lanes
  const float* kb = kbuf + (((size_t)b * HEADS + h) * NK) * HD;
  #pragma unroll 2
  for (int m = 0; m < 256; ++m) {
    const float4* kr = (const float4*)(kb + m * HD + s * 16);
    float p = 0;
    #pragma unroll
    for (int j = 0; j < 4; ++j) {
      float4 kv = kr[j];
      p += qreg[4 * j] * kv.x + qreg[4 * j + 1] * kv.y + qreg[4 * j + 2] * kv.z + qreg[4 * j + 3] * kv.w;
    }
    p += __shfl_xor(p, 1);
    p += __shfl_xor(p, 2);
    if (s == (m & 3)) lg[qi * 256 + ((m + qi * 4) & 255)] = p;  // swizzle vs banks
  }
  __syncthreads();
  // softmax within the owning 4 lanes
  float mx = -1e30f;
  for (int r = 0; r < 64; ++r) {
    int idx = (s * 64 + r + qi * 4) & 255;
    mx = fmaxf(mx, lg[qi * 256 + idx]);
  }
  mx = fmaxf(mx, __shfl_xor(mx, 1));
  mx = fmaxf(mx, __shfl_xor(mx, 2));
  float sum = 0;
  for (int r = 0; r < 64; ++r) {
    int idx = (s * 64 + r + qi * 4) & 255;
    float e = __expf(lg[qi * 256 + idx] - mx);
    lg[qi * 256 + idx] = e;
    sum += e;
  }
  sum += __shfl_xor(sum, 1);
  sum += __shfl_xor(sum, 2);
  float inv = 1.0f / sum;
  __syncthreads();

  // PV: stream v (L2-hot), weights from LDS (broadcast within query)
  const float* vb = vbuf + (((size_t)b * HEADS + h) * NK) * HD;
  float o16[16];
  #pragma unroll
  for (int i = 0; i < 16; ++i) o16[i] = 0;
  #pragma unroll 2
  for (int m = 0; m < 256; ++m) {
    float w = lg[qi * 256 + ((m + qi * 4) & 255)];
    const float4* vr = (const float4*)(vb + m * HD + s * 16);
    #pragma unroll
    for (int j = 0; j < 4; ++j) {
      float4 vv = vr[j];
      o16[4 * j]     += w * vv.x; o16[4 * j + 1] += w * vv.y;
      o16[4 * j + 2] += w * vv.z; o16[4 * j + 3] += w * vv.w;
    }
  }
  float4* op = (float4*)(out + ((size_t)b * NN + n) * CC + h * 64 + s * 16);
  #pragma unroll
  for (int j = 0; j < 4; ++j)
    op[j] = make_float4(o16[4 * j] * inv, o16[4 * j + 1] * inv,
                        o16[4 * j + 2] * inv, o16[4 * j + 3] * inv);
}

// 4096 blocks x 256 thr: in-place out = out @ proj_w.T + proj_b (32 rows/block)
__global__ __launch_bounds__(256) void proj_inplace(
    float* __restrict__ out, const float* __restrict__ pwT,
    const float* __restrict__ proj_b) {
  __shared__ float a[32 * 132];   // padded stride 132 to spread banks
  const int t = threadIdx.x;
  const size_t base = (size_t)blockIdx.x * 32 * 128;
  #pragma unroll
  for (int it = 0; it < 4; ++it) {
    int flat4 = it * 256 + t;       // 0..1023 float4s
    int m = flat4 >> 5, c4 = flat4 & 31;
    ((float4*)&a[m * 132])[c4] = ((const float4*)(out + base))[flat4];
  }
  __syncthreads();
  const int m  = t >> 3;
  const int ob = (t & 7) * 16;
  float acc[16];
  #pragma unroll
  for (int i = 0; i < 16; ++i) acc[i] = proj_b[ob + i];
  for (int c = 0; c < 128; ++c) {
    float av = a[m * 132 + c];
    const float4* pw = (const float4*)(pwT + c * 128 + ob);
    #pragma unroll
    for (int j = 0; j < 4; ++j) {
      float4 w = pw[j];
      acc[4 * j]     += av * w.x; acc[4 * j + 1] += av * w.y;
      acc[4 * j + 2] += av * w.z; acc[4 * j + 3] += av * w.w;
    }
  }
  float4* op = (float4*)(out + base + m * 128 + ob);
  #pragma unroll
  for (int j = 0; j < 4; ++j)
    op[j] = make_float4(acc[4 * j], acc[4 * j + 1], acc[4 * j + 2], acc[4 * j + 3]);
}

extern "C" void kernel_launch(void* const* d_in, const int* in_sizes, int n_in,
                              void* d_out, int out_size, void* d_ws, size_t ws_size,
                              hipStream_t stream) {
  const float* x      = (const float*)d_in[0];
  const float* q_w    = (const float*)d_in[3];
  const float* q_b    = (const float*)d_in[4];
  const float* kv_w   = (const float*)d_in[5];
  const float* kv_b   = (const float*)d_in[6];
  const float* sr_w   = (const float*)d_in[7];
  const float* ln_g   = (const float*)d_in[8];
  const float* ln_b   = (const float*)d_in[9];
  const float* proj_w = (const float*)d_in[10];
  const float* proj_b = (const float*)d_in[11];
  float* out = (float*)d_out;
  float* ws  = (float*)d_ws;

  hipLaunchKernelGGL(prep_w, dim3(4096), dim3(256), 0, stream, sr_w, proj_w, kv_w, ws);
  hipLaunchKernelGGL(conv_ln_kv, dim3(256), dim3(512), 0, stream,
                     x, ws + OFF_WT, ws + OFF_KVWT, kv_b, ln_g, ln_b,
                     ws + OFF_K, ws + OFF_V);
  hipLaunchKernelGGL(attn_fused, dim3(4096), dim3(256), 0, stream,
                     x, q_w, q_b, ws + OFF_K, ws + OFF_V, out);
  hipLaunchKernelGGL(proj_inplace, dim3(4096), dim3(256), 0, stream,
                     out, ws + OFF_PWT, proj_b);
}

// Round 2
// 1253.977 us; speedup vs baseline: 2.7527x; 2.7527x over previous
//
#include <hip/hip_runtime.h>
#include <cstdint>

#define BB 8
#define NN 16384
#define CC 128
#define HEADS 2
#define HD 64
#define NK 256

// workspace offsets (in floats)
#define OFF_WT   0          // conv weight transposed: [k=p*128+c][o]  8192*128
#define OFF_PWT  1048576    // proj_w transposed: [c][o]               128*128
#define OFF_KVWT 1064960    // kv_w transposed: [c][kvo]               128*256
#define OFF_QWT  1097728    // q_w transposed: [c][o]                  128*128
#define OFF_K    1114112    // [B][H][NK][HD] f32                      262144
#define OFF_V    1376256    // [B][H][NK][HD] f32                      262144

typedef __attribute__((ext_vector_type(8))) __bf16 bf16x8;
typedef __attribute__((ext_vector_type(16))) float f32x16;

union U4 { uint32_t u[4]; uint4 q; bf16x8 v; };

__device__ __forceinline__ uint32_t cvt_pk_bf16(float lo, float hi) {
  uint32_t r;
  asm("v_cvt_pk_bf16_f32 %0, %1, %2" : "=v"(r) : "v"(lo), "v"(hi));
  return r;
}
__device__ __forceinline__ void permswap(uint32_t& a, uint32_t& b) {
  asm("v_permlane32_swap_b32 %0, %1" : "+v"(a), "+v"(b));
}

__global__ __launch_bounds__(256) void prep_w(
    const float* __restrict__ sr_w, const float* __restrict__ proj_w,
    const float* __restrict__ kv_w, const float* __restrict__ q_w,
    float* __restrict__ ws) {
  int tid = blockIdx.x * 256 + threadIdx.x;   // grid 4096*256 = 1048576 exactly
  {
    int o = tid & 127, k = tid >> 7;
    int c = k & 127, p = k >> 7;              // p = di*8+dj
    ws[OFF_WT + tid] = sr_w[o * 8192 + c * 64 + p];
  }
  if (tid < 128 * 128) {
    int o = tid & 127, c = tid >> 7;
    ws[OFF_PWT + c * 128 + o] = proj_w[o * 128 + c];
    ws[OFF_QWT + c * 128 + o] = q_w[o * 128 + c];
  }
  if (tid < 256 * 128) {
    int kvo = tid & 255, c = tid >> 8;
    ws[OFF_KVWT + c * 256 + kvo] = kv_w[kvo * 128 + c];
  }
}

// 256 blocks (b, 8-token tile) x 512 threads. (unchanged from prev round)
__global__ __launch_bounds__(512) void conv_ln_kv(
    const float* __restrict__ x, const float* __restrict__ wT,
    const float* __restrict__ kvwT, const float* __restrict__ kv_b,
    const float* __restrict__ ln_g, const float* __restrict__ ln_b,
    float* __restrict__ kbuf, float* __restrict__ vbuf) {
  __shared__ float xs[8192];      // [1024 k][8 tokens] 32KB
  __shared__ float tok[8 * 128];  // 4KB
  const int t = threadIdx.x;
  const int b = blockIdx.x >> 5;
  const int tile = blockIdx.x & 31;

  const int o  = t & 127;
  const int qq = t >> 7;
  const int mh = qq & 1;
  const int kh = qq >> 1;

  float acc0 = 0, acc1 = 0, acc2 = 0, acc3 = 0;

  for (int kc = 0; kc < 8; ++kc) {
    __syncthreads();
    #pragma unroll
    for (int it = 0; it < 2; ++it) {
      int kl = it * 512 + t;
      int c  = kl & 127;
      int pl = kl >> 7;
      int p  = kc * 8 + pl;
      int di = p >> 3, dj = p & 7;
      float v[8];
      #pragma unroll
      for (int tm = 0; tm < 8; ++tm) {
        int nk = tile * 8 + tm;
        int ti = nk >> 4, tj = nk & 15;
        int n  = (ti * 8 + di) * 128 + (tj * 8 + dj);
        v[tm] = x[((size_t)b * NN + n) * CC + c];
      }
      float4* dst = (float4*)&xs[kl * 8];
      dst[0] = make_float4(v[0], v[1], v[2], v[3]);
      dst[1] = make_float4(v[4], v[5], v[6], v[7]);
    }
    __syncthreads();
    const float*  wrow = wT + (size_t)(kc * 1024 + kh * 512) * 128 + o;
    const float4* xsp  = (const float4*)&xs[kh * 512 * 8 + mh * 4];
    #pragma unroll 4
    for (int kl = 0; kl < 512; ++kl) {
      float  w  = wrow[(size_t)kl * 128];
      float4 xv = xsp[kl * 2];
      acc0 += xv.x * w; acc1 += xv.y * w; acc2 += xv.z * w; acc3 += xv.w * w;
    }
  }
  if (kh == 0) {
    tok[(mh * 4 + 0) * 128 + o] = acc0; tok[(mh * 4 + 1) * 128 + o] = acc1;
    tok[(mh * 4 + 2) * 128 + o] = acc2; tok[(mh * 4 + 3) * 128 + o] = acc3;
  }
  __syncthreads();
  if (kh == 1) {
    tok[(mh * 4 + 0) * 128 + o] += acc0; tok[(mh * 4 + 1) * 128 + o] += acc1;
    tok[(mh * 4 + 2) * 128 + o] += acc2; tok[(mh * 4 + 3) * 128 + o] += acc3;
  }
  __syncthreads();
  if (t < 256) {
    int m = t >> 5, j = t & 31;
    float s = 0, ss = 0;
    #pragma unroll
    for (int c = j; c < 128; c += 32) { float vv = tok[m * 128 + c]; s += vv; ss += vv * vv; }
    #pragma unroll
    for (int w = 16; w; w >>= 1) { s += __shfl_xor(s, w); ss += __shfl_xor(ss, w); }
    float mu  = s * 0.0078125f;
    float var = fmaxf(ss * 0.0078125f - mu * mu, 0.f);
    float rs  = rsqrtf(var + 1e-5f);
    #pragma unroll
    for (int c = j; c < 128; c += 32) {
      float vv = tok[m * 128 + c];
      tok[m * 128 + c] = (vv - mu) * rs * ln_g[c] + ln_b[c];
    }
  }
  __syncthreads();
  {
    int kvo = t & 255, mhf = t >> 8;
    float a0 = 0, a1 = 0, a2 = 0, a3 = 0;
    for (int c = 0; c < 128; ++c) {
      float w = kvwT[c * 256 + kvo];
      a0 += tok[(mhf * 4 + 0) * 128 + c] * w;
      a1 += tok[(mhf * 4 + 1) * 128 + c] * w;
      a2 += tok[(mhf * 4 + 2) * 128 + c] * w;
      a3 += tok[(mhf * 4 + 3) * 128 + c] * w;
    }
    float bias = kv_b[kvo];
    int two = kvo >> 7, h = (kvo >> 6) & 1, d = kvo & 63;
    float* ob = two ? vbuf : kbuf;
    size_t base = (((size_t)b * HEADS + h) * NK + tile * 8 + mhf * 4) * HD + d;
    ob[base]          = a0 + bias;
    ob[base + HD]     = a1 + bias;
    ob[base + 2 * HD] = a2 + bias;
    ob[base + 3 * HD] = a3 + bias;
  }
}

// Q projection (fp32 VALU): qout = (x @ q_w.T + q_b) * SCALE, written into d_out.
__global__ __launch_bounds__(256) void qproj(
    const float* __restrict__ x, const float* __restrict__ qwT,
    const float* __restrict__ q_b, float* __restrict__ qout) {
  __shared__ float a[32 * 132];
  const int t = threadIdx.x;
  const size_t base = (size_t)blockIdx.x * 32 * 128;
  #pragma unroll
  for (int it = 0; it < 4; ++it) {
    int flat4 = it * 256 + t;
    int m = flat4 >> 5, c4 = flat4 & 31;
    ((float4*)&a[m * 132])[c4] = ((const float4*)(x + base))[flat4];
  }
  __syncthreads();
  const int m = t >> 3, obp = (t & 7) * 16;
  float acc[16];
  #pragma unroll
  for (int i = 0; i < 16; ++i) acc[i] = q_b[obp + i];
  for (int c = 0; c < 128; ++c) {
    float av = a[m * 132 + c];
    const float4* pw = (const float4*)(qwT + c * 128 + obp);
    #pragma unroll
    for (int j = 0; j < 4; ++j) {
      float4 w = pw[j];
      acc[4 * j]     += av * w.x; acc[4 * j + 1] += av * w.y;
      acc[4 * j + 2] += av * w.z; acc[4 * j + 3] += av * w.w;
    }
  }
  float4* op = (float4*)(qout + base + m * 128 + obp);
  #pragma unroll
  for (int j = 0; j < 4; ++j)
    op[j] = make_float4(acc[4 * j] * 0.125f, acc[4 * j + 1] * 0.125f,
                        acc[4 * j + 2] * 0.125f, acc[4 * j + 3] * 0.125f);
}

// MFMA attention: 2048 blocks = (bh 16) x (128-query tile 128), 256 thr = 4 waves.
// Wave owns 32 queries. S^T = mfma(K, Q^T) so the key axis is lane-local;
// softmax in registers; P repacked via cvt_pk + permlane32_swap; O = mfma(P, V).
__global__ __launch_bounds__(256, 2) void attn_mfma(
    const float* __restrict__ qsrc, const float* __restrict__ kbuf,
    const float* __restrict__ vbuf, float* __restrict__ out) {
  __shared__ __align__(16) char lds[65536];  // [0,32K) K bf16 swz; [32K,64K) V^T bf16 swz
  const int t  = threadIdx.x;
  const int l  = t & 63, wid = t >> 6;
  const int lq = l & 31, lh = l >> 5;
  const int bh = blockIdx.x >> 7;
  const int b  = bh >> 1, h = bh & 1;
  const int qbase = (blockIdx.x & 127) * 128;

  // ---- Phase A: stage this wave's 32 Q rows into per-wave LDS scratch ----
  {
    const float* q0 = qsrc + ((size_t)b * NN + qbase + wid * 32) * CC + h * 64;
    #pragma unroll
    for (int it = 0; it < 8; ++it) {
      int flat = it * 64 + l;
      int r = flat >> 4, j = flat & 15;     // 16 float4 per 64-dim row
      float4 xv = *(const float4*)(q0 + r * CC + j * 4);
      int byte = wid * 4096 + ((r * 128 + j * 8) ^ ((r & 7) << 4));
      *(uint2*)(lds + byte) = make_uint2(cvt_pk_bf16(xv.x, xv.y), cvt_pk_bf16(xv.z, xv.w));
    }
  }
  __syncthreads();
  U4 qb[4];   // B-operand frags: Q^T[dim][q], lane holds q=lq, dims kg*16+lh*8..+7
  #pragma unroll
  for (int kg = 0; kg < 4; ++kg) {
    int byte = wid * 4096 + ((lq * 128 + kg * 32 + lh * 16) ^ ((lq & 7) << 4));
    qb[kg].q = *(const uint4*)(lds + byte);
  }
  __syncthreads();

  // ---- Phase B: stage K [256][64] and V^T [64][256] as swizzled bf16 ----
  {
    const float* kb = kbuf + (size_t)bh * NK * HD;
    #pragma unroll
    for (int it = 0; it < 16; ++it) {
      int flat = it * 256 + t;
      int key = flat >> 4, j = flat & 15;
      float4 kv = *(const float4*)(kb + key * HD + j * 4);
      int byte = (key * 128 + j * 8) ^ ((key & 7) << 4);
      *(uint2*)(lds + byte) = make_uint2(cvt_pk_bf16(kv.x, kv.y), cvt_pk_bf16(kv.z, kv.w));
    }
    const float* vb = vbuf + (size_t)bh * NK * HD;
    int d = t & 63, kb4 = t >> 6;
    #pragma unroll
    for (int k0 = 0; k0 < 64; k0 += 4) {
      int k = kb4 * 64 + k0;
      float v0 = vb[(k + 0) * HD + d], v1 = vb[(k + 1) * HD + d];
      float v2 = vb[(k + 2) * HD + d], v3 = vb[(k + 3) * HD + d];
      int byte = 32768 + ((d * 512 + k * 2) ^ ((d & 7) << 4));
      *(uint2*)(lds + byte) = make_uint2(cvt_pk_bf16(v0, v1), cvt_pk_bf16(v2, v3));
    }
  }
  __syncthreads();

  // ---- Phase C: S^T = K · Q^T  (8 key-tiles x 4 mfma) ----
  f32x16 p[8];
  #pragma unroll
  for (int kt = 0; kt < 8; ++kt) p[kt] = (f32x16)0.0f;
  #pragma unroll
  for (int kt = 0; kt < 8; ++kt) {
    const int key = kt * 32 + lq;
    #pragma unroll
    for (int kg = 0; kg < 4; ++kg) {
      U4 a;
      int byte = (key * 128 + kg * 32 + lh * 16) ^ ((key & 7) << 4);
      a.q = *(const uint4*)(lds + byte);
      p[kt] = __builtin_amdgcn_mfma_f32_32x32x16_bf16(a.v, qb[kg].v, p[kt], 0, 0, 0);
    }
  }

  // ---- Phase D: softmax (key axis lane-local; one shfl to join halves) ----
  float mx = -1e30f;
  #pragma unroll
  for (int kt = 0; kt < 8; ++kt)
    #pragma unroll
    for (int i = 0; i < 16; ++i) mx = fmaxf(mx, p[kt][i]);
  mx = fmaxf(mx, __shfl_xor(mx, 32));
  float sum = 0.f;
  #pragma unroll
  for (int kt = 0; kt < 8; ++kt)
    #pragma unroll
    for (int i = 0; i < 16; ++i) { float e = __expf(p[kt][i] - mx); p[kt][i] = e; sum += e; }
  sum += __shfl_xor(sum, 32);
  const float inv = 1.f / sum;
  #pragma unroll
  for (int kt = 0; kt < 8; ++kt)
    #pragma unroll
    for (int i = 0; i < 16; ++i) p[kt][i] *= inv;

  // ---- Phase E: O = P · V  (P repacked in-register to A-frags) ----
  f32x16 oacc0 = (f32x16)0.0f, oacc1 = (f32x16)0.0f;
  #pragma unroll
  for (int kt = 0; kt < 8; ++kt) {
    uint32_t x0 = cvt_pk_bf16(p[kt][0],  p[kt][1]);
    uint32_t x1 = cvt_pk_bf16(p[kt][2],  p[kt][3]);
    uint32_t y0 = cvt_pk_bf16(p[kt][4],  p[kt][5]);
    uint32_t y1 = cvt_pk_bf16(p[kt][6],  p[kt][7]);
    permswap(x0, y0); permswap(x1, y1);
    U4 pa0; pa0.u[0] = x0; pa0.u[1] = x1; pa0.u[2] = y0; pa0.u[3] = y1;
    uint32_t x2 = cvt_pk_bf16(p[kt][8],  p[kt][9]);
    uint32_t x3 = cvt_pk_bf16(p[kt][10], p[kt][11]);
    uint32_t y2 = cvt_pk_bf16(p[kt][12], p[kt][13]);
    uint32_t y3 = cvt_pk_bf16(p[kt][14], p[kt][15]);
    permswap(x2, y2); permswap(x3, y3);
    U4 pa1; pa1.u[0] = x2; pa1.u[1] = x3; pa1.u[2] = y2; pa1.u[3] = y3;
    #pragma unroll
    for (int dt = 0; dt < 2; ++dt) {
      int d = dt * 32 + lq;
      U4 vb0, vb1;
      int byte0 = 32768 + ((d * 512 + kt * 64 + lh * 16) ^ ((d & 7) << 4));
      int byte1 = 32768 + ((d * 512 + kt * 64 + 32 + lh * 16) ^ ((d & 7) << 4));
      vb0.q = *(const uint4*)(lds + byte0);
      vb1.q = *(const uint4*)(lds + byte1);
      f32x16& oa = dt ? oacc1 : oacc0;
      oa = __builtin_amdgcn_mfma_f32_32x32x16_bf16(pa0.v, vb0.v, oa, 0, 0, 0);
      oa = __builtin_amdgcn_mfma_f32_32x32x16_bf16(pa1.v, vb1.v, oa, 0, 0, 0);
    }
  }

  // ---- Phase F: coalesced store (overwrites this block's own Q region) ----
  float* ob = out + ((size_t)b * NN + qbase + wid * 32) * CC + h * 64;
  #pragma unroll
  for (int reg = 0; reg < 16; ++reg) {
    int q = (reg & 3) + 8 * (reg >> 2) + 4 * lh;
    ob[q * CC + lq]      = oacc0[reg];
    ob[q * CC + 32 + lq] = oacc1[reg];
  }
}

// 4096 blocks x 256 thr: in-place out = out @ proj_w.T + proj_b (32 rows/block)
__global__ __launch_bounds__(256) void proj_inplace(
    float* __restrict__ out, const float* __restrict__ pwT,
    const float* __restrict__ proj_b) {
  __shared__ float a[32 * 132];
  const int t = threadIdx.x;
  const size_t base = (size_t)blockIdx.x * 32 * 128;
  #pragma unroll
  for (int it = 0; it < 4; ++it) {
    int flat4 = it * 256 + t;
    int m = flat4 >> 5, c4 = flat4 & 31;
    ((float4*)&a[m * 132])[c4] = ((const float4*)(out + base))[flat4];
  }
  __syncthreads();
  const int m  = t >> 3;
  const int ob = (t & 7) * 16;
  float acc[16];
  #pragma unroll
  for (int i = 0; i < 16; ++i) acc[i] = proj_b[ob + i];
  for (int c = 0; c < 128; ++c) {
    float av = a[m * 132 + c];
    const float4* pw = (const float4*)(pwT + c * 128 + ob);
    #pragma unroll
    for (int j = 0; j < 4; ++j) {
      float4 w = pw[j];
      acc[4 * j]     += av * w.x; acc[4 * j + 1] += av * w.y;
      acc[4 * j + 2] += av * w.z; acc[4 * j + 3] += av * w.w;
    }
  }
  float4* op = (float4*)(out + base + m * 128 + ob);
  #pragma unroll
  for (int j = 0; j < 4; ++j)
    op[j] = make_float4(acc[4 * j], acc[4 * j + 1], acc[4 * j + 2], acc[4 * j + 3]);
}

extern "C" void kernel_launch(void* const* d_in, const int* in_sizes, int n_in,
                              void* d_out, int out_size, void* d_ws, size_t ws_size,
                              hipStream_t stream) {
  const float* x      = (const float*)d_in[0];
  const float* q_w    = (const float*)d_in[3];
  const float* q_b    = (const float*)d_in[4];
  const float* kv_w   = (const float*)d_in[5];
  const float* kv_b   = (const float*)d_in[6];
  const float* sr_w   = (const float*)d_in[7];
  const float* ln_g   = (const float*)d_in[8];
  const float* ln_b   = (const float*)d_in[9];
  const float* proj_w = (const float*)d_in[10];
  const float* proj_b = (const float*)d_in[11];
  float* out = (float*)d_out;
  float* ws  = (float*)d_ws;

  hipLaunchKernelGGL(prep_w, dim3(4096), dim3(256), 0, stream, sr_w, proj_w, kv_w, q_w, ws);
  hipLaunchKernelGGL(conv_ln_kv, dim3(256), dim3(512), 0, stream,
                     x, ws + OFF_WT, ws + OFF_KVWT, kv_b, ln_g, ln_b,
                     ws + OFF_K, ws + OFF_V);
  hipLaunchKernelGGL(qproj, dim3(4096), dim3(256), 0, stream,
                     x, ws + OFF_QWT, q_b, out);
  hipLaunchKernelGGL(attn_mfma, dim3(2048), dim3(256), 0, stream,
                     out, ws + OFF_K, ws + OFF_V, out);
  hipLaunchKernelGGL(proj_inplace, dim3(4096), dim3(256), 0, stream,
                     out, ws + OFF_PWT, proj_b);
}

// Round 4
// 375.865 us; speedup vs baseline: 9.1836x; 3.3362x over previous
//
#include <hip/hip_runtime.h>
#include <cstdint>

#define BB 8
#define NN 16384
#define CC 128
#define HEADS 2
#define HD 64
#define NK 256

// workspace offsets (in floats)
#define OFF_WT   0          // conv weight transposed: [k=p*128+c][o]   8192*128
#define OFF_KVWT 1048576    // kv_w transposed: [c][kvo]                128*256
#define OFF_K    1081344    // [B][H][NK][HD] f32                       262144
#define OFF_V    1343488    // [B][H][NK][HD] f32                       262144
#define OFF_QF   1605632    // q_w MFMA B-frags, 8192 uint32
#define OFF_PF   1613824    // proj_w MFMA B-frags, 8192 uint32

typedef __attribute__((ext_vector_type(8))) __bf16 bf16x8;
typedef __attribute__((ext_vector_type(16))) float f32x16;

union U4 { uint32_t u[4]; uint4 q; bf16x8 v; };

__device__ __forceinline__ uint32_t cvt_pk_bf16(float lo, float hi) {
  uint32_t r;
  asm("v_cvt_pk_bf16_f32 %0, %1, %2" : "=v"(r) : "v"(lo), "v"(hi));
  return r;
}
__device__ __forceinline__ void permswap(uint32_t& a, uint32_t& b) {
  asm("v_permlane32_swap_b32 %0, %1" : "+v"(a), "+v"(b));
}

__global__ __launch_bounds__(256) void prep_w(
    const float* __restrict__ sr_w, const float* __restrict__ proj_w,
    const float* __restrict__ kv_w, const float* __restrict__ q_w,
    float* __restrict__ ws) {
  int tid = blockIdx.x * 256 + threadIdx.x;   // grid 4096*256 = 1048576 exactly
  {
    int o = tid & 127, k = tid >> 7;
    int c = k & 127, p = k >> 7;              // p = di*8+dj
    ws[OFF_WT + tid] = sr_w[o * 8192 + c * 64 + p];
  }
  if (tid < 256 * 128) {
    int kvo = tid & 255, c = tid >> 8;
    ws[OFF_KVWT + c * 256 + kvo] = kv_w[kvo * 128 + c];
  }
  // MFMA B-frag tables for q_w and proj_w (8192 uint32 each):
  // u = ks*1024 + nt*256 + l*4 + jp ; lane l word jp holds
  // B[k=ks*16+(l>>5)*8+jp*2 (+1)][o=nt*32+(l&31)] = W[o][k]
  if (tid < 16384) {
    const float* W = (tid < 8192) ? q_w : proj_w;
    uint32_t* dst = (uint32_t*)(ws + ((tid < 8192) ? OFF_QF : OFF_PF));
    int u  = tid & 8191;
    int jp = u & 3, l = (u >> 2) & 63, nt = (u >> 8) & 3, ks = u >> 10;  // ks in [0,8)
    int k = ks * 16 + (l >> 5) * 8 + jp * 2;
    int o = nt * 32 + (l & 31);
    dst[u] = cvt_pk_bf16(W[o * 128 + k], W[o * 128 + k + 1]);
  }
}

// 256 blocks (b, 8-token tile) x 512 threads. fp32 conv + LN + KV proj.
__global__ __launch_bounds__(512) void conv_ln_kv(
    const float* __restrict__ x, const float* __restrict__ wT,
    const float* __restrict__ kvwT, const float* __restrict__ kv_b,
    const float* __restrict__ ln_g, const float* __restrict__ ln_b,
    float* __restrict__ kbuf, float* __restrict__ vbuf) {
  __shared__ float xs[8192];      // [1024 k][8 tokens] 32KB
  __shared__ float tok[8 * 128];  // 4KB
  const int t = threadIdx.x;
  const int b = blockIdx.x >> 5;
  const int tile = blockIdx.x & 31;

  const int o  = t & 127;
  const int qq = t >> 7;
  const int mh = qq & 1;
  const int kh = qq >> 1;

  float acc0 = 0, acc1 = 0, acc2 = 0, acc3 = 0;

  for (int kc = 0; kc < 8; ++kc) {
    __syncthreads();
    #pragma unroll
    for (int it = 0; it < 2; ++it) {
      int kl = it * 512 + t;
      int c  = kl & 127;
      int pl = kl >> 7;
      int p  = kc * 8 + pl;
      int di = p >> 3, dj = p & 7;
      float v[8];
      #pragma unroll
      for (int tm = 0; tm < 8; ++tm) {
        int nk = tile * 8 + tm;
        int ti = nk >> 4, tj = nk & 15;
        int n  = (ti * 8 + di) * 128 + (tj * 8 + dj);
        v[tm] = x[((size_t)b * NN + n) * CC + c];
      }
      float4* dst = (float4*)&xs[kl * 8];
      dst[0] = make_float4(v[0], v[1], v[2], v[3]);
      dst[1] = make_float4(v[4], v[5], v[6], v[7]);
    }
    __syncthreads();
    const float*  wrow = wT + (size_t)(kc * 1024 + kh * 512) * 128 + o;
    const float4* xsp  = (const float4*)&xs[kh * 512 * 8 + mh * 4];
    #pragma unroll 4
    for (int kl = 0; kl < 512; ++kl) {
      float  w  = wrow[(size_t)kl * 128];
      float4 xv = xsp[kl * 2];
      acc0 += xv.x * w; acc1 += xv.y * w; acc2 += xv.z * w; acc3 += xv.w * w;
    }
  }
  if (kh == 0) {
    tok[(mh * 4 + 0) * 128 + o] = acc0; tok[(mh * 4 + 1) * 128 + o] = acc1;
    tok[(mh * 4 + 2) * 128 + o] = acc2; tok[(mh * 4 + 3) * 128 + o] = acc3;
  }
  __syncthreads();
  if (kh == 1) {
    tok[(mh * 4 + 0) * 128 + o] += acc0; tok[(mh * 4 + 1) * 128 + o] += acc1;
    tok[(mh * 4 + 2) * 128 + o] += acc2; tok[(mh * 4 + 3) * 128 + o] += acc3;
  }
  __syncthreads();
  if (t < 256) {
    int m = t >> 5, j = t & 31;
    float s = 0, ss = 0;
    #pragma unroll
    for (int c = j; c < 128; c += 32) { float vv = tok[m * 128 + c]; s += vv; ss += vv * vv; }
    #pragma unroll
    for (int w = 16; w; w >>= 1) { s += __shfl_xor(s, w); ss += __shfl_xor(ss, w); }
    float mu  = s * 0.0078125f;
    float var = fmaxf(ss * 0.0078125f - mu * mu, 0.f);
    float rs  = rsqrtf(var + 1e-5f);
    #pragma unroll
    for (int c = j; c < 128; c += 32) {
      float vv = tok[m * 128 + c];
      tok[m * 128 + c] = (vv - mu) * rs * ln_g[c] + ln_b[c];
    }
  }
  __syncthreads();
  {
    int kvo = t & 255, mhf = t >> 8;
    float a0 = 0, a1 = 0, a2 = 0, a3 = 0;
    for (int c = 0; c < 128; ++c) {
      float w = kvwT[c * 256 + kvo];
      a0 += tok[(mhf * 4 + 0) * 128 + c] * w;
      a1 += tok[(mhf * 4 + 1) * 128 + c] * w;
      a2 += tok[(mhf * 4 + 2) * 128 + c] * w;
      a3 += tok[(mhf * 4 + 3) * 128 + c] * w;
    }
    float bias = kv_b[kvo];
    int two = kvo >> 7, h = (kvo >> 6) & 1, d = kvo & 63;
    float* ob = two ? vbuf : kbuf;
    size_t base = (((size_t)b * HEADS + h) * NK + tile * 8 + mhf * 4) * HD + d;
    ob[base]          = a0 + bias;
    ob[base + HD]     = a1 + bias;
    ob[base + 2 * HD] = a2 + bias;
    ob[base + 3 * HD] = a3 + bias;
  }
}

// Thin MFMA GEMM: Y[M,128] = (bf16(X[M,128]) @ fragsW + bias) * scale.
// 1024 blocks x 256 thr (4 waves); wave = 32 rows x 128 cols; no LDS, no barriers.
// In-place safe (wave reads only its own rows, stores after all reads).
__global__ __launch_bounds__(256) void gemm128(
    const float* X, const uint32_t* __restrict__ frags,
    const float* __restrict__ bias, float scale, float* Y) {
  const int t = threadIdx.x;
  const int l = t & 63, wid = t >> 6;
  const int lq = l & 31, lh = l >> 5;
  const size_t rowbase = (size_t)blockIdx.x * 128 + wid * 32;
  const float* xrow = X + (rowbase + lq) * CC;

  f32x16 acc[4];
  #pragma unroll
  for (int nt = 0; nt < 4; ++nt) acc[nt] = (f32x16)0.0f;

  #pragma unroll
  for (int ks = 0; ks < 8; ++ks) {
    float4 a0 = *(const float4*)(xrow + ks * 16 + lh * 8);
    float4 a1 = *(const float4*)(xrow + ks * 16 + lh * 8 + 4);
    U4 af;
    af.u[0] = cvt_pk_bf16(a0.x, a0.y); af.u[1] = cvt_pk_bf16(a0.z, a0.w);
    af.u[2] = cvt_pk_bf16(a1.x, a1.y); af.u[3] = cvt_pk_bf16(a1.z, a1.w);
    #pragma unroll
    for (int nt = 0; nt < 4; ++nt) {
      U4 bf_;
      bf_.q = *(const uint4*)(frags + ((ks * 4 + nt) * 64 + l) * 4);
      acc[nt] = __builtin_amdgcn_mfma_f32_32x32x16_bf16(af.v, bf_.v, acc[nt], 0, 0, 0);
    }
  }
  #pragma unroll
  for (int nt = 0; nt < 4; ++nt) {
    int o = nt * 32 + lq;
    float bv = bias[o];
    #pragma unroll
    for (int r = 0; r < 16; ++r) {
      int m = (r & 3) + 8 * (r >> 2) + 4 * lh;
      Y[(rowbase + m) * CC + o] = (acc[nt][r] + bv) * scale;
    }
  }
}

// MFMA attention: 2048 blocks = (bh 16) x (128-query tile), 256 thr = 4 waves.
__global__ __launch_bounds__(256, 2) void attn_mfma(
    const float* __restrict__ qsrc, const float* __restrict__ kbuf,
    const float* __restrict__ vbuf, float* __restrict__ out) {
  __shared__ __align__(16) char lds[65536];  // [0,32K) K bf16 swz; [32K,64K) V^T bf16 swz
  const int t  = threadIdx.x;
  const int l  = t & 63, wid = t >> 6;
  const int lq = l & 31, lh = l >> 5;
  const int bh = blockIdx.x >> 7;
  const int b  = bh >> 1, h = bh & 1;
  const int qbase = (blockIdx.x & 127) * 128;

  // ---- Phase A: Q B-frags straight from global fp32 ----
  U4 qb[4];   // Q^T[dim][q]: lane holds q=lq, dims kg*16+lh*8..+7
  {
    const float* q0 = qsrc + ((size_t)b * NN + qbase + wid * 32 + lq) * CC + h * 64;
    #pragma unroll
    for (int kg = 0; kg < 4; ++kg) {
      float4 x0 = *(const float4*)(q0 + kg * 16 + lh * 8);
      float4 x1 = *(const float4*)(q0 + kg * 16 + lh * 8 + 4);
      qb[kg].u[0] = cvt_pk_bf16(x0.x, x0.y); qb[kg].u[1] = cvt_pk_bf16(x0.z, x0.w);
      qb[kg].u[2] = cvt_pk_bf16(x1.x, x1.y); qb[kg].u[3] = cvt_pk_bf16(x1.z, x1.w);
    }
  }

  // ---- Phase B: stage K [256][64] and V^T [64][256] as swizzled bf16 ----
  {
    const float* kb = kbuf + (size_t)bh * NK * HD;
    #pragma unroll
    for (int it = 0; it < 16; ++it) {
      int flat = it * 256 + t;
      int key = flat >> 4, j = flat & 15;
      float4 kv = *(const float4*)(kb + key * HD + j * 4);
      int byte = (key * 128 + j * 8) ^ ((key & 7) << 4);
      *(uint2*)(lds + byte) = make_uint2(cvt_pk_bf16(kv.x, kv.y), cvt_pk_bf16(kv.z, kv.w));
    }
    const float* vb = vbuf + (size_t)bh * NK * HD;
    int d = t & 63, kb4 = t >> 6;
    #pragma unroll
    for (int k0 = 0; k0 < 64; k0 += 4) {
      int k = kb4 * 64 + k0;
      float v0 = vb[(k + 0) * HD + d], v1 = vb[(k + 1) * HD + d];
      float v2 = vb[(k + 2) * HD + d], v3 = vb[(k + 3) * HD + d];
      int byte = 32768 + ((d * 512 + k * 2) ^ ((d & 7) << 4));
      *(uint2*)(lds + byte) = make_uint2(cvt_pk_bf16(v0, v1), cvt_pk_bf16(v2, v3));
    }
  }
  __syncthreads();

  // ---- Phase C: S^T = K · Q^T ----
  f32x16 p[8];
  #pragma unroll
  for (int kt = 0; kt < 8; ++kt) p[kt] = (f32x16)0.0f;
  #pragma unroll
  for (int kt = 0; kt < 8; ++kt) {
    const int key = kt * 32 + lq;
    #pragma unroll
    for (int kg = 0; kg < 4; ++kg) {
      U4 a;
      int byte = (key * 128 + kg * 32 + lh * 16) ^ ((key & 7) << 4);
      a.q = *(const uint4*)(lds + byte);
      p[kt] = __builtin_amdgcn_mfma_f32_32x32x16_bf16(a.v, qb[kg].v, p[kt], 0, 0, 0);
    }
  }

  // ---- Phase D: softmax (key axis lane-local; one shfl to join halves) ----
  float mx = -1e30f;
  #pragma unroll
  for (int kt = 0; kt < 8; ++kt)
    #pragma unroll
    for (int i = 0; i < 16; ++i) mx = fmaxf(mx, p[kt][i]);
  mx = fmaxf(mx, __shfl_xor(mx, 32));
  float sum = 0.f;
  #pragma unroll
  for (int kt = 0; kt < 8; ++kt)
    #pragma unroll
    for (int i = 0; i < 16; ++i) { float e = __expf(p[kt][i] - mx); p[kt][i] = e; sum += e; }
  sum += __shfl_xor(sum, 32);
  const float inv = 1.f / sum;
  #pragma unroll
  for (int kt = 0; kt < 8; ++kt)
    #pragma unroll
    for (int i = 0; i < 16; ++i) p[kt][i] *= inv;

  // ---- Phase E: O = P · V ----
  f32x16 oacc0 = (f32x16)0.0f, oacc1 = (f32x16)0.0f;
  #pragma unroll
  for (int kt = 0; kt < 8; ++kt) {
    uint32_t x0 = cvt_pk_bf16(p[kt][0],  p[kt][1]);
    uint32_t x1 = cvt_pk_bf16(p[kt][2],  p[kt][3]);
    uint32_t y0 = cvt_pk_bf16(p[kt][4],  p[kt][5]);
    uint32_t y1 = cvt_pk_bf16(p[kt][6],  p[kt][7]);
    permswap(x0, y0); permswap(x1, y1);
    U4 pa0; pa0.u[0] = x0; pa0.u[1] = x1; pa0.u[2] = y0; pa0.u[3] = y1;
    uint32_t x2 = cvt_pk_bf16(p[kt][8],  p[kt][9]);
    uint32_t x3 = cvt_pk_bf16(p[kt][10], p[kt][11]);
    uint32_t y2 = cvt_pk_bf16(p[kt][12], p[kt][13]);
    uint32_t y3 = cvt_pk_bf16(p[kt][14], p[kt][15]);
    permswap(x2, y2); permswap(x3, y3);
    U4 pa1; pa1.u[0] = x2; pa1.u[1] = x3; pa1.u[2] = y2; pa1.u[3] = y3;
    #pragma unroll
    for (int dt = 0; dt < 2; ++dt) {
      int d = dt * 32 + lq;
      U4 vb0, vb1;
      int byte0 = 32768 + ((d * 512 + kt * 64 + lh * 16) ^ ((d & 7) << 4));
      int byte1 = 32768 + ((d * 512 + kt * 64 + 32 + lh * 16) ^ ((d & 7) << 4));
      vb0.q = *(const uint4*)(lds + byte0);
      vb1.q = *(const uint4*)(lds + byte1);
      f32x16& oa = dt ? oacc1 : oacc0;
      oa = __builtin_amdgcn_mfma_f32_32x32x16_bf16(pa0.v, vb0.v, oa, 0, 0, 0);
      oa = __builtin_amdgcn_mfma_f32_32x32x16_bf16(pa1.v, vb1.v, oa, 0, 0, 0);
    }
  }

  // ---- Phase F: coalesced store (overwrites this block's own Q region) ----
  float* ob = out + ((size_t)b * NN + qbase + wid * 32) * CC + h * 64;
  #pragma unroll
  for (int reg = 0; reg < 16; ++reg) {
    int q = (reg & 3) + 8 * (reg >> 2) + 4 * lh;
    ob[q * CC + lq]      = oacc0[reg];
    ob[q * CC + 32 + lq] = oacc1[reg];
  }
}

extern "C" void kernel_launch(void* const* d_in, const int* in_sizes, int n_in,
                              void* d_out, int out_size, void* d_ws, size_t ws_size,
                              hipStream_t stream) {
  const float* x      = (const float*)d_in[0];
  const float* q_w    = (const float*)d_in[3];
  const float* q_b    = (const float*)d_in[4];
  const float* kv_w   = (const float*)d_in[5];
  const float* kv_b   = (const float*)d_in[6];
  const float* sr_w   = (const float*)d_in[7];
  const float* ln_g   = (const float*)d_in[8];
  const float* ln_b   = (const float*)d_in[9];
  const float* proj_w = (const float*)d_in[10];
  const float* proj_b = (const float*)d_in[11];
  float* out = (float*)d_out;
  float* ws  = (float*)d_ws;

  hipLaunchKernelGGL(prep_w, dim3(4096), dim3(256), 0, stream, sr_w, proj_w, kv_w, q_w, ws);
  hipLaunchKernelGGL(conv_ln_kv, dim3(256), dim3(512), 0, stream,
                     x, ws + OFF_WT, ws + OFF_KVWT, kv_b, ln_g, ln_b,
                     ws + OFF_K, ws + OFF_V);
  hipLaunchKernelGGL(gemm128, dim3(1024), dim3(256), 0, stream,
                     x, (const uint32_t*)(ws + OFF_QF), q_b, 0.125f, out);
  hipLaunchKernelGGL(attn_mfma, dim3(2048), dim3(256), 0, stream,
                     out, ws + OFF_K, ws + OFF_V, out);
  hipLaunchKernelGGL(gemm128, dim3(1024), dim3(256), 0, stream,
                     out, (const uint32_t*)(ws + OFF_PF), proj_b, 1.0f, out);
}

// Round 5
// 134.264 us; speedup vs baseline: 25.7090x; 2.7994x over previous
//
#include <hip/hip_runtime.h>
#include <cstdint>

#define BB 8
#define NN 16384
#define CC 128
#define HEADS 2
#define HD 64
#define NK 256

// workspace offsets (in floats)
#define OFF_CF   0          // conv B-frags (16x16x32): [ks 256][nt 8][l 64][jp 4] u32 = 524288
#define OFF_KVF  524288     // kv B-frags (16x16x32): [ks 4][nt 16][l 64][jp 4] u32 = 16384
#define OFF_QF   540672     // q_w frags (32x32x16): 8192 u32
#define OFF_PF   548864     // proj_w frags (32x32x16): 8192 u32
#define OFF_K    557056     // K [B][H][NK][HD] f32 = 262144
#define OFF_V    819200     // V [B][H][NK][HD] f32 = 262144
// total 1081344 floats = 4.3 MB

typedef __attribute__((ext_vector_type(8))) __bf16 bf16x8;
typedef __attribute__((ext_vector_type(16))) float f32x16;
typedef __attribute__((ext_vector_type(4))) float f32x4;

union U4 { uint32_t u[4]; uint4 q; bf16x8 v; };

__device__ __forceinline__ uint32_t cvt_pk_bf16(float lo, float hi) {
  uint32_t r;
  asm("v_cvt_pk_bf16_f32 %0, %1, %2" : "=v"(r) : "v"(lo), "v"(hi));
  return r;
}
__device__ __forceinline__ void permswap(uint32_t& a, uint32_t& b) {
  asm("v_permlane32_swap_b32 %0, %1" : "+v"(a), "+v"(b));
}

// grid 2176 x 256 = 557056 threads exactly
__global__ __launch_bounds__(256) void prep_w(
    const float* __restrict__ sr_w, const float* __restrict__ proj_w,
    const float* __restrict__ kv_w, const float* __restrict__ q_w,
    float* __restrict__ ws) {
  int tid = blockIdx.x * 256 + threadIdx.x;
  if (tid < 524288) {
    // conv frag: B[k][o] = sr_w[o][c=k&127][p=k>>7] ; k = ks*32 + kg*8 + jp*2
    int u = tid;
    int jp = u & 3, l = (u >> 2) & 63, nt = (u >> 8) & 7, ks = u >> 11;
    int k = ks * 32 + ((l >> 4) & 3) * 8 + jp * 2;
    int o = nt * 16 + (l & 15);
    int c = k & 127, p = k >> 7;
    ((uint32_t*)(ws + OFF_CF))[u] =
        cvt_pk_bf16(sr_w[o * 8192 + c * 64 + p], sr_w[o * 8192 + (c + 1) * 64 + p]);
  } else if (tid < 540672) {
    // kv frag: B[k][kvo] = kv_w[kvo][k]
    int u = tid - 524288;
    int jp = u & 3, l = (u >> 2) & 63, nt = (u >> 8) & 15, ks = u >> 12;
    int k = ks * 32 + ((l >> 4) & 3) * 8 + jp * 2;
    int o = nt * 16 + (l & 15);
    ((uint32_t*)(ws + OFF_KVF))[u] = cvt_pk_bf16(kv_w[o * 128 + k], kv_w[o * 128 + k + 1]);
  } else {
    // q_w / proj_w frags (32x32x16 layout, as validated in rounds 2-4)
    int u = tid - 540672;
    const float* W = (u < 8192) ? q_w : proj_w;
    uint32_t* dst = (uint32_t*)(ws + ((u < 8192) ? OFF_QF : OFF_PF));
    u &= 8191;
    int jp = u & 3, l = (u >> 2) & 63, nt = (u >> 8) & 3, ks = u >> 10;
    int k = ks * 16 + (l >> 5) * 8 + jp * 2;
    int o = nt * 32 + (l & 31);
    dst[u] = cvt_pk_bf16(W[o * 128 + k], W[o * 128 + k + 1]);
  }
}

// Fused conv (as MFMA GEMM, split-K across waves) + LN + KV projection.
// 128 blocks x 512 thr (8 waves). Block = 16 tokens (one b, one ti row).
// Wave w covers pixel-row di=w (K-slice 1024). Wave-private LDS staging ->
// no barriers in main loop. Then LDS tree-reduce, LN, 16x16x32 KV GEMM.
__global__ __launch_bounds__(512, 2) void conv_mfma(
    const float* __restrict__ x, const uint32_t* __restrict__ cf,
    const uint32_t* __restrict__ kvf, const float* __restrict__ kv_b,
    const float* __restrict__ ln_g, const float* __restrict__ ln_b,
    float* __restrict__ kbuf, float* __restrict__ vbuf) {
  extern __shared__ __align__(16) char lds[];
  // [0,32K): per-wave stage [16 tok][256B bf16] swz ; [32K,64K): rbuf 4x[16][128] f32
  // [64K,68K): abuf [16 tok][256B bf16] swz (LN'd tokens)
  const int t = threadIdx.x;
  const int l = t & 63, w = t >> 6;
  const int tg0 = blockIdx.x * 16;         // 16 tokens: same b, same ti, tj=0..15
  const int b   = tg0 >> 8;
  const int nk0 = tg0 & 255;
  const int ti  = nk0 >> 4;
  char* sreg = lds + w * 4096;
  const int col = l & 15, kg = (l >> 4) & 3;   // A-frag row / k-group, C col / row-group

  f32x4 acc[8];
  #pragma unroll
  for (int nt = 0; nt < 8; ++nt) acc[nt] = (f32x4)0.0f;

  for (int sub = 0; sub < 8; ++sub) {      // pixel (ti*8+w, tj*8+sub), 128 ch
    #pragma unroll
    for (int it = 0; it < 4; ++it) {
      int flat = it * 64 + l;
      int tk = flat >> 4, c16 = flat & 15; // token, 8-ch chunk
      const float* src = x + ((size_t)b * NN + ((ti * 8 + w) * 128 + tk * 8 + sub)) * CC + c16 * 8;
      float4 a0 = *(const float4*)(src);
      float4 a1 = *(const float4*)(src + 4);
      U4 pk;
      pk.u[0] = cvt_pk_bf16(a0.x, a0.y); pk.u[1] = cvt_pk_bf16(a0.z, a0.w);
      pk.u[2] = cvt_pk_bf16(a1.x, a1.y); pk.u[3] = cvt_pk_bf16(a1.z, a1.w);
      *(uint4*)(sreg + tk * 256 + ((c16 * 16) ^ ((tk & 7) << 4))) = pk.q;
    }
    const int ksg0 = (w * 8 + sub) * 4;
    #pragma unroll
    for (int ksl = 0; ksl < 4; ++ksl) {
      U4 a;
      a.q = *(const uint4*)(sreg + col * 256 + ((ksl * 64 + kg * 16) ^ ((col & 7) << 4)));
      #pragma unroll
      for (int nt = 0; nt < 8; ++nt) {
        U4 bf_;
        bf_.q = *(const uint4*)(cf + (((ksg0 + ksl) * 8 + nt) * 64 + l) * 4);
        acc[nt] = __builtin_amdgcn_mfma_f32_16x16x32_bf16(a.v, bf_.v, acc[nt], 0, 0, 0);
      }
    }
  }

  // cross-wave K-reduce: 8 -> 4 -> 2 -> 1 through rbuf
  float* rbuf = (float*)(lds + 32768);
  if (w >= 4) {
    float* dst = rbuf + (w - 4) * 2048;
    #pragma unroll
    for (int nt = 0; nt < 8; ++nt)
      #pragma unroll
      for (int r = 0; r < 4; ++r) dst[(kg * 4 + r) * 128 + nt * 16 + col] = acc[nt][r];
  }
  __syncthreads();
  if (w < 4) {
    const float* s1 = rbuf + w * 2048;
    #pragma unroll
    for (int nt = 0; nt < 8; ++nt)
      #pragma unroll
      for (int r = 0; r < 4; ++r) acc[nt][r] += s1[(kg * 4 + r) * 128 + nt * 16 + col];
    if (w >= 2) {
      float* dst = rbuf + w * 2048;
      #pragma unroll
      for (int nt = 0; nt < 8; ++nt)
        #pragma unroll
        for (int r = 0; r < 4; ++r) dst[(kg * 4 + r) * 128 + nt * 16 + col] = acc[nt][r];
    }
  }
  __syncthreads();
  if (w < 2) {
    const float* s2 = rbuf + (w + 2) * 2048;
    #pragma unroll
    for (int nt = 0; nt < 8; ++nt)
      #pragma unroll
      for (int r = 0; r < 4; ++r) acc[nt][r] += s2[(kg * 4 + r) * 128 + nt * 16 + col];
    if (w == 1) {
      float* dst = rbuf + 2048;
      #pragma unroll
      for (int nt = 0; nt < 8; ++nt)
        #pragma unroll
        for (int r = 0; r < 4; ++r) dst[(kg * 4 + r) * 128 + nt * 16 + col] = acc[nt][r];
    }
  }
  __syncthreads();
  if (w == 0) {
    const float* s3 = rbuf + 2048;
    #pragma unroll
    for (int nt = 0; nt < 8; ++nt)
      #pragma unroll
      for (int r = 0; r < 4; ++r) acc[nt][r] += s3[(kg * 4 + r) * 128 + nt * 16 + col];
    #pragma unroll
    for (int nt = 0; nt < 8; ++nt)
      #pragma unroll
      for (int r = 0; r < 4; ++r) rbuf[(kg * 4 + r) * 128 + nt * 16 + col] = acc[nt][r];
  }
  __syncthreads();

  // LayerNorm over channels: 512 thr = 16 tokens x 32 lanes x 4 ch
  char* abuf = lds + 65536;
  {
    const int tk = t >> 5, j = t & 31;
    float4 v4 = *(const float4*)(rbuf + tk * 128 + j * 4);
    float s  = v4.x + v4.y + v4.z + v4.w;
    float ss = v4.x * v4.x + v4.y * v4.y + v4.z * v4.z + v4.w * v4.w;
    #pragma unroll
    for (int m = 16; m; m >>= 1) { s += __shfl_xor(s, m); ss += __shfl_xor(ss, m); }
    float mu  = s * 0.0078125f;
    float var = fmaxf(ss * 0.0078125f - mu * mu, 0.f);
    float rs  = rsqrtf(var + 1e-5f);
    float4 g4 = *(const float4*)(ln_g + j * 4);
    float4 b4 = *(const float4*)(ln_b + j * 4);
    float y0 = (v4.x - mu) * rs * g4.x + b4.x;
    float y1 = (v4.y - mu) * rs * g4.y + b4.y;
    float y2 = (v4.z - mu) * rs * g4.z + b4.z;
    float y3 = (v4.w - mu) * rs * g4.w + b4.w;
    uint2 pk = make_uint2(cvt_pk_bf16(y0, y1), cvt_pk_bf16(y2, y3));
    *(uint2*)(abuf + tk * 256 + ((j * 8) ^ ((tk & 7) << 4))) = pk;
  }
  __syncthreads();

  // KV projection: M=16 tokens, N=256, K=128 ; wave w -> kvo tiles {2w, 2w+1}
  f32x4 kacc[2];
  kacc[0] = (f32x4)0.0f; kacc[1] = (f32x4)0.0f;
  #pragma unroll
  for (int ks = 0; ks < 4; ++ks) {
    U4 a;
    a.q = *(const uint4*)(abuf + col * 256 + ((ks * 64 + kg * 16) ^ ((col & 7) << 4)));
    #pragma unroll
    for (int i = 0; i < 2; ++i) {
      int nt = w * 2 + i;
      U4 bf_;
      bf_.q = *(const uint4*)(kvf + ((ks * 16 + nt) * 64 + l) * 4);
      kacc[i] = __builtin_amdgcn_mfma_f32_16x16x32_bf16(a.v, bf_.v, kacc[i], 0, 0, 0);
    }
  }
  #pragma unroll
  for (int i = 0; i < 2; ++i) {
    int kvo = (w * 2 + i) * 16 + col;
    float bias = kv_b[kvo];
    float* obuf = (kvo >= 128) ? vbuf : kbuf;
    int h = (kvo >> 6) & 1, d = kvo & 63;
    #pragma unroll
    for (int r = 0; r < 4; ++r) {
      int tkr = kg * 4 + r;
      obuf[(((size_t)b * HEADS + h) * NK + nk0 + tkr) * HD + d] = kacc[i][r] + bias;
    }
  }
}

// Thin MFMA GEMM: Y[M,128] = (bf16(X[M,128]) @ fragsW + bias) * scale.
// 1024 blocks x 256 thr (4 waves); wave = 32 rows x 128 cols; no LDS, no barriers.
__global__ __launch_bounds__(256) void gemm128(
    const float* X, const uint32_t* __restrict__ frags,
    const float* __restrict__ bias, float scale, float* Y) {
  const int t = threadIdx.x;
  const int l = t & 63, wid = t >> 6;
  const int lq = l & 31, lh = l >> 5;
  const size_t rowbase = (size_t)blockIdx.x * 128 + wid * 32;
  const float* xrow = X + (rowbase + lq) * CC;

  f32x16 acc[4];
  #pragma unroll
  for (int nt = 0; nt < 4; ++nt) acc[nt] = (f32x16)0.0f;

  #pragma unroll
  for (int ks = 0; ks < 8; ++ks) {
    float4 a0 = *(const float4*)(xrow + ks * 16 + lh * 8);
    float4 a1 = *(const float4*)(xrow + ks * 16 + lh * 8 + 4);
    U4 af;
    af.u[0] = cvt_pk_bf16(a0.x, a0.y); af.u[1] = cvt_pk_bf16(a0.z, a0.w);
    af.u[2] = cvt_pk_bf16(a1.x, a1.y); af.u[3] = cvt_pk_bf16(a1.z, a1.w);
    #pragma unroll
    for (int nt = 0; nt < 4; ++nt) {
      U4 bf_;
      bf_.q = *(const uint4*)(frags + ((ks * 4 + nt) * 64 + l) * 4);
      acc[nt] = __builtin_amdgcn_mfma_f32_32x32x16_bf16(af.v, bf_.v, acc[nt], 0, 0, 0);
    }
  }
  #pragma unroll
  for (int nt = 0; nt < 4; ++nt) {
    int o = nt * 32 + lq;
    float bv = bias[o];
    #pragma unroll
    for (int r = 0; r < 16; ++r) {
      int m = (r & 3) + 8 * (r >> 2) + 4 * lh;
      Y[(rowbase + m) * CC + o] = (acc[nt][r] + bv) * scale;
    }
  }
}

// MFMA attention: 2048 blocks = (bh 16) x (128-query tile), 256 thr = 4 waves.
__global__ __launch_bounds__(256, 2) void attn_mfma(
    const float* __restrict__ qsrc, const float* __restrict__ kbuf,
    const float* __restrict__ vbuf, float* __restrict__ out) {
  __shared__ __align__(16) char lds[65536];  // [0,32K) K bf16 swz; [32K,64K) V^T bf16 swz
  const int t  = threadIdx.x;
  const int l  = t & 63, wid = t >> 6;
  const int lq = l & 31, lh = l >> 5;
  const int bh = blockIdx.x >> 7;
  const int b  = bh >> 1, h = bh & 1;
  const int qbase = (blockIdx.x & 127) * 128;

  // ---- Phase A: Q B-frags straight from global fp32 ----
  U4 qb[4];
  {
    const float* q0 = qsrc + ((size_t)b * NN + qbase + wid * 32 + lq) * CC + h * 64;
    #pragma unroll
    for (int kg = 0; kg < 4; ++kg) {
      float4 x0 = *(const float4*)(q0 + kg * 16 + lh * 8);
      float4 x1 = *(const float4*)(q0 + kg * 16 + lh * 8 + 4);
      qb[kg].u[0] = cvt_pk_bf16(x0.x, x0.y); qb[kg].u[1] = cvt_pk_bf16(x0.z, x0.w);
      qb[kg].u[2] = cvt_pk_bf16(x1.x, x1.y); qb[kg].u[3] = cvt_pk_bf16(x1.z, x1.w);
    }
  }

  // ---- Phase B: stage K [256][64] and V^T [64][256] as swizzled bf16 ----
  {
    const float* kb = kbuf + (size_t)bh * NK * HD;
    #pragma unroll
    for (int it = 0; it < 16; ++it) {
      int flat = it * 256 + t;
      int key = flat >> 4, j = flat & 15;
      float4 kv = *(const float4*)(kb + key * HD + j * 4);
      int byte = (key * 128 + j * 8) ^ ((key & 7) << 4);
      *(uint2*)(lds + byte) = make_uint2(cvt_pk_bf16(kv.x, kv.y), cvt_pk_bf16(kv.z, kv.w));
    }
    const float* vb = vbuf + (size_t)bh * NK * HD;
    int d = t & 63, kb4 = t >> 6;
    #pragma unroll
    for (int k0 = 0; k0 < 64; k0 += 4) {
      int k = kb4 * 64 + k0;
      float v0 = vb[(k + 0) * HD + d], v1 = vb[(k + 1) * HD + d];
      float v2 = vb[(k + 2) * HD + d], v3 = vb[(k + 3) * HD + d];
      int byte = 32768 + ((d * 512 + k * 2) ^ ((d & 7) << 4));
      *(uint2*)(lds + byte) = make_uint2(cvt_pk_bf16(v0, v1), cvt_pk_bf16(v2, v3));
    }
  }
  __syncthreads();

  // ---- Phase C: S^T = K · Q^T ----
  f32x16 p[8];
  #pragma unroll
  for (int kt = 0; kt < 8; ++kt) p[kt] = (f32x16)0.0f;
  #pragma unroll
  for (int kt = 0; kt < 8; ++kt) {
    const int key = kt * 32 + lq;
    #pragma unroll
    for (int kg = 0; kg < 4; ++kg) {
      U4 a;
      int byte = (key * 128 + kg * 32 + lh * 16) ^ ((key & 7) << 4);
      a.q = *(const uint4*)(lds + byte);
      p[kt] = __builtin_amdgcn_mfma_f32_32x32x16_bf16(a.v, qb[kg].v, p[kt], 0, 0, 0);
    }
  }

  // ---- Phase D: softmax (key axis lane-local; one shfl to join halves) ----
  float mx = -1e30f;
  #pragma unroll
  for (int kt = 0; kt < 8; ++kt)
    #pragma unroll
    for (int i = 0; i < 16; ++i) mx = fmaxf(mx, p[kt][i]);
  mx = fmaxf(mx, __shfl_xor(mx, 32));
  float sum = 0.f;
  #pragma unroll
  for (int kt = 0; kt < 8; ++kt)
    #pragma unroll
    for (int i = 0; i < 16; ++i) { float e = __expf(p[kt][i] - mx); p[kt][i] = e; sum += e; }
  sum += __shfl_xor(sum, 32);
  const float inv = 1.f / sum;
  #pragma unroll
  for (int kt = 0; kt < 8; ++kt)
    #pragma unroll
    for (int i = 0; i < 16; ++i) p[kt][i] *= inv;

  // ---- Phase E: O = P · V ----
  f32x16 oacc0 = (f32x16)0.0f, oacc1 = (f32x16)0.0f;
  #pragma unroll
  for (int kt = 0; kt < 8; ++kt) {
    uint32_t x0 = cvt_pk_bf16(p[kt][0],  p[kt][1]);
    uint32_t x1 = cvt_pk_bf16(p[kt][2],  p[kt][3]);
    uint32_t y0 = cvt_pk_bf16(p[kt][4],  p[kt][5]);
    uint32_t y1 = cvt_pk_bf16(p[kt][6],  p[kt][7]);
    permswap(x0, y0); permswap(x1, y1);
    U4 pa0; pa0.u[0] = x0; pa0.u[1] = x1; pa0.u[2] = y0; pa0.u[3] = y1;
    uint32_t x2 = cvt_pk_bf16(p[kt][8],  p[kt][9]);
    uint32_t x3 = cvt_pk_bf16(p[kt][10], p[kt][11]);
    uint32_t y2 = cvt_pk_bf16(p[kt][12], p[kt][13]);
    uint32_t y3 = cvt_pk_bf16(p[kt][14], p[kt][15]);
    permswap(x2, y2); permswap(x3, y3);
    U4 pa1; pa1.u[0] = x2; pa1.u[1] = x3; pa1.u[2] = y2; pa1.u[3] = y3;
    #pragma unroll
    for (int dt = 0; dt < 2; ++dt) {
      int d = dt * 32 + lq;
      U4 vb0, vb1;
      int byte0 = 32768 + ((d * 512 + kt * 64 + lh * 16) ^ ((d & 7) << 4));
      int byte1 = 32768 + ((d * 512 + kt * 64 + 32 + lh * 16) ^ ((d & 7) << 4));
      vb0.q = *(const uint4*)(lds + byte0);
      vb1.q = *(const uint4*)(lds + byte1);
      f32x16& oa = dt ? oacc1 : oacc0;
      oa = __builtin_amdgcn_mfma_f32_32x32x16_bf16(pa0.v, vb0.v, oa, 0, 0, 0);
      oa = __builtin_amdgcn_mfma_f32_32x32x16_bf16(pa1.v, vb1.v, oa, 0, 0, 0);
    }
  }

  // ---- Phase F: coalesced store (overwrites this block's own Q region) ----
  float* ob = out + ((size_t)b * NN + qbase + wid * 32) * CC + h * 64;
  #pragma unroll
  for (int reg = 0; reg < 16; ++reg) {
    int q = (reg & 3) + 8 * (reg >> 2) + 4 * lh;
    ob[q * CC + lq]      = oacc0[reg];
    ob[q * CC + 32 + lq] = oacc1[reg];
  }
}

extern "C" void kernel_launch(void* const* d_in, const int* in_sizes, int n_in,
                              void* d_out, int out_size, void* d_ws, size_t ws_size,
                              hipStream_t stream) {
  const float* x      = (const float*)d_in[0];
  const float* q_w    = (const float*)d_in[3];
  const float* q_b    = (const float*)d_in[4];
  const float* kv_w   = (const float*)d_in[5];
  const float* kv_b   = (const float*)d_in[6];
  const float* sr_w   = (const float*)d_in[7];
  const float* ln_g   = (const float*)d_in[8];
  const float* ln_b   = (const float*)d_in[9];
  const float* proj_w = (const float*)d_in[10];
  const float* proj_b = (const float*)d_in[11];
  float* out = (float*)d_out;
  float* ws  = (float*)d_ws;

  hipLaunchKernelGGL(prep_w, dim3(2176), dim3(256), 0, stream, sr_w, proj_w, kv_w, q_w, ws);
  hipLaunchKernelGGL(conv_mfma, dim3(128), dim3(512), 69632, stream,
                     x, (const uint32_t*)(ws + OFF_CF), (const uint32_t*)(ws + OFF_KVF),
                     kv_b, ln_g, ln_b, ws + OFF_K, ws + OFF_V);
  hipLaunchKernelGGL(gemm128, dim3(1024), dim3(256), 0, stream,
                     x, (const uint32_t*)(ws + OFF_QF), q_b, 0.125f, out);
  hipLaunchKernelGGL(attn_mfma, dim3(2048), dim3(256), 0, stream,
                     out, ws + OFF_K, ws + OFF_V, out);
  hipLaunchKernelGGL(gemm128, dim3(1024), dim3(256), 0, stream,
                     out, (const uint32_t*)(ws + OFF_PF), proj_b, 1.0f, out);
}

// Round 8
// 120.995 us; speedup vs baseline: 28.5283x; 1.1097x over previous
//
#include <hip/hip_runtime.h>
#include <cstdint>

#define BB 8
#define NN 16384
#define CC 128
#define HEADS 2
#define HD 64
#define NK 256

// workspace offsets (in float/u32 slots)
#define OFF_CF   0          // conv B-frags 16x16x32: [ks 256][nt 8][l 64][jp 4] = 524288
#define OFF_KVF  524288     // kv B-frags 16x16x32: [ks 4][nt 16][l 64][jp 4]   = 16384
#define OFF_QF   540672     // q_w B-frags 32x32x16: [ks 8][nt 4][l 64][jp 4]   = 8192
#define OFF_PF   548864     // proj_w B-frags 32x32x16: [ks 8][nt 4][l 64][jp 4] = 8192
#define OFF_K    557056     // K f32 [bh 16][256][64] = 262144
#define OFF_V    819200     // V f32 [bh 16][256][64] = 262144
#define OFF_PART 1081344    // conv partials f32 [nq][128][2048]

typedef __attribute__((ext_vector_type(8))) __bf16 bf16x8;
typedef __attribute__((ext_vector_type(16))) float f32x16;
typedef __attribute__((ext_vector_type(4))) float f32x4;

union U4 { uint32_t u[4]; uint4 q; bf16x8 v; };

__device__ __forceinline__ uint32_t cvt_pk_bf16(float lo, float hi) {
  uint32_t r;
  asm("v_cvt_pk_bf16_f32 %0, %1, %2" : "=v"(r) : "v"(lo), "v"(hi));
  return r;
}
__device__ __forceinline__ void permswap(uint32_t& a, uint32_t& b) {
  asm("v_permlane32_swap_b32 %0, %1" : "+v"(a), "+v"(b));
}

// grid 2176 x 256 = 557056 exactly  (verbatim round-5 semantics)
__global__ __launch_bounds__(256) void prep_w(
    const float* __restrict__ sr_w, const float* __restrict__ proj_w,
    const float* __restrict__ kv_w, const float* __restrict__ q_w,
    float* __restrict__ ws) {
  int tid = blockIdx.x * 256 + threadIdx.x;
  if (tid < 524288) {
    // conv frag: B[k][o] = sr_w[o][c=k&127][p=k>>7] ; k = ks*32 + kg*8 + jp*2
    int u = tid;
    int jp = u & 3, l = (u >> 2) & 63, nt = (u >> 8) & 7, ks = u >> 11;
    int k = ks * 32 + ((l >> 4) & 3) * 8 + jp * 2;
    int o = nt * 16 + (l & 15);
    int c = k & 127, p = k >> 7;
    ((uint32_t*)(ws + OFF_CF))[u] =
        cvt_pk_bf16(sr_w[o * 8192 + c * 64 + p], sr_w[o * 8192 + (c + 1) * 64 + p]);
  } else if (tid < 540672) {
    // kv frag: B[k][kvo] = kv_w[kvo][k]
    int u = tid - 524288;
    int jp = u & 3, l = (u >> 2) & 63, nt = (u >> 8) & 15, ks = u >> 12;
    int k = ks * 32 + ((l >> 4) & 3) * 8 + jp * 2;
    int o = nt * 16 + (l & 15);
    ((uint32_t*)(ws + OFF_KVF))[u] = cvt_pk_bf16(kv_w[o * 128 + k], kv_w[o * 128 + k + 1]);
  } else if (tid < 548864) {
    // q_w B-frag (32x32x16), validated rounds 4-5
    int u = tid - 540672;
    int jp = u & 3, l = (u >> 2) & 63, nt = (u >> 8) & 3, ks = u >> 10;
    int k = ks * 16 + (l >> 5) * 8 + jp * 2;
    int o = nt * 32 + (l & 31);
    ((uint32_t*)(ws + OFF_QF))[u] = cvt_pk_bf16(q_w[o * 128 + k], q_w[o * 128 + k + 1]);
  } else {
    // proj_w B-frag (32x32x16), validated rounds 4-5
    int u = tid - 548864;
    int jp = u & 3, l = (u >> 2) & 63, nt = (u >> 8) & 3, ks = u >> 10;
    int k = ks * 16 + (l >> 5) * 8 + jp * 2;
    int o = nt * 32 + (l & 31);
    ((uint32_t*)(ws + OFF_PF))[u] = cvt_pk_bf16(proj_w[o * 128 + k], proj_w[o * 128 + k + 1]);
  }
}

// Conv as MFMA GEMM with split-K across blocks (the ONLY change vs round 5).
// grid 128*NQ x 512 thr (8 waves). Block = 16 tokens; K-slice = pixel cols
// [khq*NSUB, +NSUB); wave w = pixel row di=w. Wave-private LDS staging.
template<int NSUB>
__global__ __launch_bounds__(512, 2) void conv_partial(
    const float* __restrict__ x, const uint32_t* __restrict__ cf,
    float* __restrict__ partial) {
  extern __shared__ __align__(16) char lds[];  // [0,32K) sreg 8x4K; [32K,64K) rbuf
  const int t = threadIdx.x;
  const int l = t & 63, w = t >> 6;
  const int NQ = 8 / NSUB;
  const int tile = blockIdx.x / NQ;      // 0..127
  const int khq  = blockIdx.x % NQ;
  const int b  = tile >> 4;
  const int ti = tile & 15;
  char* sreg = lds + w * 4096;
  const int col = l & 15, kg = (l >> 4) & 3;

  f32x4 acc[8];
  #pragma unroll
  for (int nt = 0; nt < 8; ++nt) acc[nt] = (f32x4)0.0f;

  #pragma unroll
  for (int si = 0; si < NSUB; ++si) {
    const int sub = khq * NSUB + si;     // pixel col dj
    #pragma unroll
    for (int it = 0; it < 4; ++it) {
      int flat = it * 64 + l;
      int tk = flat >> 4, c16 = flat & 15;
      const float* src = x + ((size_t)b * NN + ((ti * 8 + w) * 128 + tk * 8 + sub)) * CC + c16 * 8;
      float4 a0 = *(const float4*)(src);
      float4 a1 = *(const float4*)(src + 4);
      U4 pk;
      pk.u[0] = cvt_pk_bf16(a0.x, a0.y); pk.u[1] = cvt_pk_bf16(a0.z, a0.w);
      pk.u[2] = cvt_pk_bf16(a1.x, a1.y); pk.u[3] = cvt_pk_bf16(a1.z, a1.w);
      *(uint4*)(sreg + tk * 256 + ((c16 * 16) ^ ((tk & 7) << 4))) = pk.q;
    }
    const int ksg0 = (w * 8 + sub) * 4;
    #pragma unroll
    for (int ksl = 0; ksl < 4; ++ksl) {
      U4 a;
      a.q = *(const uint4*)(sreg + col * 256 + ((ksl * 64 + kg * 16) ^ ((col & 7) << 4)));
      #pragma unroll
      for (int nt = 0; nt < 8; ++nt) {
        U4 bf_;
        bf_.q = *(const uint4*)(cf + (((ksg0 + ksl) * 8 + nt) * 64 + l) * 4);
        acc[nt] = __builtin_amdgcn_mfma_f32_16x16x32_bf16(a.v, bf_.v, acc[nt], 0, 0, 0);
      }
    }
  }

  // cross-wave reduce 8 -> 1 through rbuf (verbatim round-5 tree)
  float* rbuf = (float*)(lds + 32768);
  if (w >= 4) {
    float* dst = rbuf + (w - 4) * 2048;
    #pragma unroll
    for (int nt = 0; nt < 8; ++nt)
      #pragma unroll
      for (int r = 0; r < 4; ++r) dst[(kg * 4 + r) * 128 + nt * 16 + col] = acc[nt][r];
  }
  __syncthreads();
  if (w < 4) {
    const float* s1 = rbuf + w * 2048;
    #pragma unroll
    for (int nt = 0; nt < 8; ++nt)
      #pragma unroll
      for (int r = 0; r < 4; ++r) acc[nt][r] += s1[(kg * 4 + r) * 128 + nt * 16 + col];
    if (w >= 2) {
      float* dst = rbuf + w * 2048;
      #pragma unroll
      for (int nt = 0; nt < 8; ++nt)
        #pragma unroll
        for (int r = 0; r < 4; ++r) dst[(kg * 4 + r) * 128 + nt * 16 + col] = acc[nt][r];
    }
  }
  __syncthreads();
  if (w < 2) {
    const float* s2 = rbuf + (w + 2) * 2048;
    #pragma unroll
    for (int nt = 0; nt < 8; ++nt)
      #pragma unroll
      for (int r = 0; r < 4; ++r) acc[nt][r] += s2[(kg * 4 + r) * 128 + nt * 16 + col];
    if (w == 1) {
      float* dst = rbuf + 2048;
      #pragma unroll
      for (int nt = 0; nt < 8; ++nt)
        #pragma unroll
        for (int r = 0; r < 4; ++r) dst[(kg * 4 + r) * 128 + nt * 16 + col] = acc[nt][r];
    }
  }
  __syncthreads();
  if (w == 0) {
    const float* s3 = rbuf + 2048;
    #pragma unroll
    for (int nt = 0; nt < 8; ++nt)
      #pragma unroll
      for (int r = 0; r < 4; ++r) {
        acc[nt][r] += s3[(kg * 4 + r) * 128 + nt * 16 + col];
        rbuf[(kg * 4 + r) * 128 + nt * 16 + col] = acc[nt][r];
      }
  }
  __syncthreads();
  float4 vv = ((const float4*)rbuf)[t];
  ((float4*)(partial + ((size_t)khq * 128 + tile) * 2048))[t] = vv;
}

// 128 blocks x 512 thr: sum NQ partials, then round-5 conv_mfma's LN+KV tail.
__global__ __launch_bounds__(512) void reduce_ln_kv(
    const float* __restrict__ partial, int nq,
    const uint32_t* __restrict__ kvf, const float* __restrict__ kv_b,
    const float* __restrict__ ln_g, const float* __restrict__ ln_b,
    float* __restrict__ kbuf, float* __restrict__ vbuf) {
  __shared__ __align__(16) char abuf[4096];   // [16 tok][256B bf16] swizzled
  const int t = threadIdx.x;
  const int l = t & 63, w = t >> 6;
  const int tile = blockIdx.x;
  const int b = tile >> 4, nk0 = (tile & 15) * 16;

  float4 a = make_float4(0.f, 0.f, 0.f, 0.f);
  for (int i = 0; i < nq; ++i) {
    float4 p = *(const float4*)(partial + ((size_t)i * 128 + tile) * 2048 + t * 4);
    a.x += p.x; a.y += p.y; a.z += p.z; a.w += p.w;
  }
  {
    const int tk = t >> 5, j = t & 31;   // t*4 == tk*128 + j*4
    float s  = a.x + a.y + a.z + a.w;
    float ss = a.x * a.x + a.y * a.y + a.z * a.z + a.w * a.w;
    #pragma unroll
    for (int m = 16; m; m >>= 1) { s += __shfl_xor(s, m); ss += __shfl_xor(ss, m); }
    float mu  = s * 0.0078125f;
    float var = fmaxf(ss * 0.0078125f - mu * mu, 0.f);
    float rs  = rsqrtf(var + 1e-5f);
    float4 g4 = *(const float4*)(ln_g + j * 4);
    float4 b4 = *(const float4*)(ln_b + j * 4);
    float y0 = (a.x - mu) * rs * g4.x + b4.x;
    float y1 = (a.y - mu) * rs * g4.y + b4.y;
    float y2 = (a.z - mu) * rs * g4.z + b4.z;
    float y3 = (a.w - mu) * rs * g4.w + b4.w;
    *(uint2*)(abuf + tk * 256 + ((j * 8) ^ ((tk & 7) << 4))) =
        make_uint2(cvt_pk_bf16(y0, y1), cvt_pk_bf16(y2, y3));
  }
  __syncthreads();

  const int col = l & 15, kg = (l >> 4) & 3;
  f32x4 kacc[2];
  kacc[0] = (f32x4)0.0f; kacc[1] = (f32x4)0.0f;
  #pragma unroll
  for (int ks = 0; ks < 4; ++ks) {
    U4 aa;
    aa.q = *(const uint4*)(abuf + col * 256 + ((ks * 64 + kg * 16) ^ ((col & 7) << 4)));
    #pragma unroll
    for (int i = 0; i < 2; ++i) {
      int nt = w * 2 + i;
      U4 bf_;
      bf_.q = *(const uint4*)(kvf + ((ks * 16 + nt) * 64 + l) * 4);
      kacc[i] = __builtin_amdgcn_mfma_f32_16x16x32_bf16(aa.v, bf_.v, kacc[i], 0, 0, 0);
    }
  }
  #pragma unroll
  for (int i = 0; i < 2; ++i) {
    int kvo = (w * 2 + i) * 16 + col;
    float bias = kv_b[kvo];
    float* obuf = (kvo >= 128) ? vbuf : kbuf;
    int h = (kvo >> 6) & 1, d = kvo & 63;
    #pragma unroll
    for (int r = 0; r < 4; ++r) {
      int tkr = kg * 4 + r;
      obuf[(((size_t)b * HEADS + h) * NK + nk0 + tkr) * HD + d] = kacc[i][r] + bias;
    }
  }
}

// Thin MFMA GEMM (verbatim rounds 2-5): Y = (bf16(X) @ fragsW + bias) * scale.
__global__ __launch_bounds__(256) void gemm128(
    const float* X, const uint32_t* __restrict__ frags,
    const float* __restrict__ bias, float scale, float* Y) {
  const int t = threadIdx.x;
  const int l = t & 63, wid = t >> 6;
  const int lq = l & 31, lh = l >> 5;
  const size_t rowbase = (size_t)blockIdx.x * 128 + wid * 32;
  const float* xrow = X + (rowbase + lq) * CC;

  f32x16 acc[4];
  #pragma unroll
  for (int nt = 0; nt < 4; ++nt) acc[nt] = (f32x16)0.0f;

  #pragma unroll
  for (int ks = 0; ks < 8; ++ks) {
    float4 a0 = *(const float4*)(xrow + ks * 16 + lh * 8);
    float4 a1 = *(const float4*)(xrow + ks * 16 + lh * 8 + 4);
    U4 af;
    af.u[0] = cvt_pk_bf16(a0.x, a0.y); af.u[1] = cvt_pk_bf16(a0.z, a0.w);
    af.u[2] = cvt_pk_bf16(a1.x, a1.y); af.u[3] = cvt_pk_bf16(a1.z, a1.w);
    #pragma unroll
    for (int nt = 0; nt < 4; ++nt) {
      U4 bf_;
      bf_.q = *(const uint4*)(frags + ((ks * 4 + nt) * 64 + l) * 4);
      acc[nt] = __builtin_amdgcn_mfma_f32_32x32x16_bf16(af.v, bf_.v, acc[nt], 0, 0, 0);
    }
  }
  #pragma unroll
  for (int nt = 0; nt < 4; ++nt) {
    int o = nt * 32 + lq;
    float bv = bias[o];
    #pragma unroll
    for (int r = 0; r < 16; ++r) {
      int m = (r & 3) + 8 * (r >> 2) + 4 * lh;
      Y[(rowbase + m) * CC + o] = (acc[nt][r] + bv) * scale;
    }
  }
}

// MFMA attention (verbatim round 5): 2048 blocks = (bh 16) x (128-query tile),
// 256 thr = 4 waves.
__global__ __launch_bounds__(256, 2) void attn_mfma(
    const float* __restrict__ qsrc, const float* __restrict__ kbuf,
    const float* __restrict__ vbuf, float* __restrict__ out) {
  __shared__ __align__(16) char lds[65536];  // [0,32K) K bf16 swz; [32K,64K) V^T bf16 swz
  const int t  = threadIdx.x;
  const int l  = t & 63, wid = t >> 6;
  const int lq = l & 31, lh = l >> 5;
  const int bh = blockIdx.x >> 7;
  const int b  = bh >> 1, h = bh & 1;
  const int qbase = (blockIdx.x & 127) * 128;

  // ---- Phase A: Q B-frags straight from global fp32 ----
  U4 qb[4];
  {
    const float* q0 = qsrc + ((size_t)b * NN + qbase + wid * 32 + lq) * CC + h * 64;
    #pragma unroll
    for (int kg = 0; kg < 4; ++kg) {
      float4 x0 = *(const float4*)(q0 + kg * 16 + lh * 8);
      float4 x1 = *(const float4*)(q0 + kg * 16 + lh * 8 + 4);
      qb[kg].u[0] = cvt_pk_bf16(x0.x, x0.y); qb[kg].u[1] = cvt_pk_bf16(x0.z, x0.w);
      qb[kg].u[2] = cvt_pk_bf16(x1.x, x1.y); qb[kg].u[3] = cvt_pk_bf16(x1.z, x1.w);
    }
  }

  // ---- Phase B: stage K [256][64] and V^T [64][256] as swizzled bf16 ----
  {
    const float* kb = kbuf + (size_t)bh * NK * HD;
    #pragma unroll
    for (int it = 0; it < 16; ++it) {
      int flat = it * 256 + t;
      int key = flat >> 4, j = flat & 15;
      float4 kv = *(const float4*)(kb + key * HD + j * 4);
      int byte = (key * 128 + j * 8) ^ ((key & 7) << 4);
      *(uint2*)(lds + byte) = make_uint2(cvt_pk_bf16(kv.x, kv.y), cvt_pk_bf16(kv.z, kv.w));
    }
    const float* vb = vbuf + (size_t)bh * NK * HD;
    int d = t & 63, kb4 = t >> 6;
    #pragma unroll
    for (int k0 = 0; k0 < 64; k0 += 4) {
      int k = kb4 * 64 + k0;
      float v0 = vb[(k + 0) * HD + d], v1 = vb[(k + 1) * HD + d];
      float v2 = vb[(k + 2) * HD + d], v3 = vb[(k + 3) * HD + d];
      int byte = 32768 + ((d * 512 + k * 2) ^ ((d & 7) << 4));
      *(uint2*)(lds + byte) = make_uint2(cvt_pk_bf16(v0, v1), cvt_pk_bf16(v2, v3));
    }
  }
  __syncthreads();

  // ---- Phase C: S^T = K · Q^T ----
  f32x16 p[8];
  #pragma unroll
  for (int kt = 0; kt < 8; ++kt) p[kt] = (f32x16)0.0f;
  #pragma unroll
  for (int kt = 0; kt < 8; ++kt) {
    const int key = kt * 32 + lq;
    #pragma unroll
    for (int kg = 0; kg < 4; ++kg) {
      U4 a;
      int byte = (key * 128 + kg * 32 + lh * 16) ^ ((key & 7) << 4);
      a.q = *(const uint4*)(lds + byte);
      p[kt] = __builtin_amdgcn_mfma_f32_32x32x16_bf16(a.v, qb[kg].v, p[kt], 0, 0, 0);
    }
  }

  // ---- Phase D: softmax ----
  float mx = -1e30f;
  #pragma unroll
  for (int kt = 0; kt < 8; ++kt)
    #pragma unroll
    for (int i = 0; i < 16; ++i) mx = fmaxf(mx, p[kt][i]);
  mx = fmaxf(mx, __shfl_xor(mx, 32));
  float sum = 0.f;
  #pragma unroll
  for (int kt = 0; kt < 8; ++kt)
    #pragma unroll
    for (int i = 0; i < 16; ++i) { float e = __expf(p[kt][i] - mx); p[kt][i] = e; sum += e; }
  sum += __shfl_xor(sum, 32);
  const float inv = 1.f / sum;
  #pragma unroll
  for (int kt = 0; kt < 8; ++kt)
    #pragma unroll
    for (int i = 0; i < 16; ++i) p[kt][i] *= inv;

  // ---- Phase E: O = P · V ----
  f32x16 oacc0 = (f32x16)0.0f, oacc1 = (f32x16)0.0f;
  #pragma unroll
  for (int kt = 0; kt < 8; ++kt) {
    uint32_t x0 = cvt_pk_bf16(p[kt][0],  p[kt][1]);
    uint32_t x1 = cvt_pk_bf16(p[kt][2],  p[kt][3]);
    uint32_t y0 = cvt_pk_bf16(p[kt][4],  p[kt][5]);
    uint32_t y1 = cvt_pk_bf16(p[kt][6],  p[kt][7]);
    permswap(x0, y0); permswap(x1, y1);
    U4 pa0; pa0.u[0] = x0; pa0.u[1] = x1; pa0.u[2] = y0; pa0.u[3] = y1;
    uint32_t x2 = cvt_pk_bf16(p[kt][8],  p[kt][9]);
    uint32_t x3 = cvt_pk_bf16(p[kt][10], p[kt][11]);
    uint32_t y2 = cvt_pk_bf16(p[kt][12], p[kt][13]);
    uint32_t y3 = cvt_pk_bf16(p[kt][14], p[kt][15]);
    permswap(x2, y2); permswap(x3, y3);
    U4 pa1; pa1.u[0] = x2; pa1.u[1] = x3; pa1.u[2] = y2; pa1.u[3] = y3;
    #pragma unroll
    for (int dt = 0; dt < 2; ++dt) {
      int d = dt * 32 + lq;
      U4 vb0, vb1;
      int byte0 = 32768 + ((d * 512 + kt * 64 + lh * 16) ^ ((d & 7) << 4));
      int byte1 = 32768 + ((d * 512 + kt * 64 + 32 + lh * 16) ^ ((d & 7) << 4));
      vb0.q = *(const uint4*)(lds + byte0);
      vb1.q = *(const uint4*)(lds + byte1);
      f32x16& oa = dt ? oacc1 : oacc0;
      oa = __builtin_amdgcn_mfma_f32_32x32x16_bf16(pa0.v, vb0.v, oa, 0, 0, 0);
      oa = __builtin_amdgcn_mfma_f32_32x32x16_bf16(pa1.v, vb1.v, oa, 0, 0, 0);
    }
  }

  // ---- Phase F: coalesced store (overwrites this block's own Q region) ----
  float* ob = out + ((size_t)b * NN + qbase + wid * 32) * CC + h * 64;
  #pragma unroll
  for (int reg = 0; reg < 16; ++reg) {
    int q = (reg & 3) + 8 * (reg >> 2) + 4 * lh;
    ob[q * CC + lq]      = oacc0[reg];
    ob[q * CC + 32 + lq] = oacc1[reg];
  }
}

extern "C" void kernel_launch(void* const* d_in, const int* in_sizes, int n_in,
                              void* d_out, int out_size, void* d_ws, size_t ws_size,
                              hipStream_t stream) {
  const float* x      = (const float*)d_in[0];
  const float* q_w    = (const float*)d_in[3];
  const float* q_b    = (const float*)d_in[4];
  const float* kv_w   = (const float*)d_in[5];
  const float* kv_b   = (const float*)d_in[6];
  const float* sr_w   = (const float*)d_in[7];
  const float* ln_g   = (const float*)d_in[8];
  const float* ln_b   = (const float*)d_in[9];
  const float* proj_w = (const float*)d_in[10];
  const float* proj_b = (const float*)d_in[11];
  float* out = (float*)d_out;
  float* ws  = (float*)d_ws;

  prep_w<<<dim3(2176), dim3(256), 0, stream>>>(sr_w, proj_w, kv_w, q_w, ws);

  int nq = 1;
  if (ws_size >= (size_t)(OFF_PART + 4 * 262144) * 4) nq = 4;
  else if (ws_size >= (size_t)(OFF_PART + 2 * 262144) * 4) nq = 2;

  const uint32_t* cf = (const uint32_t*)(ws + OFF_CF);
  float* part = ws + OFF_PART;
  if (nq == 4)
    conv_partial<2><<<dim3(512), dim3(512), 65536, stream>>>(x, cf, part);
  else if (nq == 2)
    conv_partial<4><<<dim3(256), dim3(512), 65536, stream>>>(x, cf, part);
  else
    conv_partial<8><<<dim3(128), dim3(512), 65536, stream>>>(x, cf, part);

  reduce_ln_kv<<<dim3(128), dim3(512), 0, stream>>>(
      part, nq, (const uint32_t*)(ws + OFF_KVF), kv_b, ln_g, ln_b,
      ws + OFF_K, ws + OFF_V);
  gemm128<<<dim3(1024), dim3(256), 0, stream>>>(
      x, (const uint32_t*)(ws + OFF_QF), q_b, 0.125f, out);
  attn_mfma<<<dim3(2048), dim3(256), 0, stream>>>(
      out, ws + OFF_K, ws + OFF_V, out);
  gemm128<<<dim3(1024), dim3(256), 0, stream>>>(
      out, (const uint32_t*)(ws + OFF_PF), proj_b, 1.0f, out);
}